// Round 9
// baseline (190.568 us; speedup 1.0000x reference)
//
#include <hip/hip_runtime.h>

#define TT 2048
#define BB 2
#define EE 1024
#define HH 16
#define DD 64
#define E3 3072
#define NTOK 4096

typedef unsigned short u16;
typedef _Float16 __attribute__((ext_vector_type(8))) half8;
typedef _Float16 __attribute__((ext_vector_type(4))) half4;
typedef __fp16 __attribute__((ext_vector_type(2))) fp16x2;
typedef __attribute__((ext_vector_type(4))) float f32x4;

__device__ __forceinline__ unsigned f2h(float f) {
    union { _Float16 h; u16 u; } v; v.h = (_Float16)f; return (unsigned)v.u;
}
// packed f32x2 -> f16x2 (round-toward-zero), one VALU op
__device__ __forceinline__ unsigned pkh(float a, float b) {
    union { fp16x2 h; unsigned u; } v;
    v.h = __builtin_amdgcn_cvt_pkrtz(a, b);
    return v.u;
}
__device__ __forceinline__ fp16x2 pk2(float a, float b) {
    return __builtin_amdgcn_cvt_pkrtz(a, b);
}

// async global->LDS, 16 B per lane; lds ptr must be wave-uniform
__device__ __forceinline__ void async_ld16(const u16* g, const u16* l) {
    auto gp = reinterpret_cast<const __attribute__((address_space(1))) unsigned*>(
        reinterpret_cast<uintptr_t>(g));
    auto lp = reinterpret_cast<__attribute__((address_space(3))) unsigned*>(
        reinterpret_cast<uintptr_t>(l));
    __builtin_amdgcn_global_load_lds(gp, lp, 16, 0, 0);
}

// fp32 -> f16 convert for x, qkv_w, out_w in ONE launch.
__global__ __launch_bounds__(256) void split3(
    const float* __restrict__ x, const float* __restrict__ w1,
    const float* __restrict__ w2,
    u16* __restrict__ xh, u16* __restrict__ w1h, u16* __restrict__ w2h)
{
    const int N1 = (NTOK * EE) / 4;
    const int N2 = N1 + (E3 * EE) / 4;
    int i = blockIdx.x * 256 + threadIdx.x;
    const float* src; u16* dst; int j;
    if (i < N1)      { src = x;  dst = xh;  j = i; }
    else if (i < N2) { src = w1; dst = w1h; j = i - N1; }
    else             { src = w2; dst = w2h; j = i - N2; }
    float4 v = ((const float4*)src)[j];
    *(uint2*)&dst[(size_t)j * 4] = make_uint2(
        f2h(v.x) | (f2h(v.y) << 16), f2h(v.z) | (f2h(v.w) << 16));
}

// f16 MFMA GEMM, BK=64. C[M,N] = A[M,1024] @ W[N,1024]^T + bias.
// QSCALE: q-third (n0<EE) scaled by 0.125*log2(e) so attention exp2s raw S.
// V-FUSION (F16OUT && vtp && n0>=2E): the block transposes its 128x128 tile
// through the dead sA/sB LDS and writes vt[b][h][d][t] directly, with the
// R8 coalesced read-back (8 lanes cover one d-row's 128 contiguous tokens).
// OCC: min waves/SIMD — gemm1 runs 4 blocks/CU (LDS 32KB x4 = 128KB fits,
// VGPR ~116 < 128) to fill the barrier-drain bubbles; gemm2's grid caps at
// 2/CU so it keeps 3.
template <int WMT, bool QSCALE, bool F16OUT, int OCC>
__global__ __launch_bounds__(256, OCC) void gemm_f16(
    const u16* __restrict__ Ag, const u16* __restrict__ Wg,
    const float* __restrict__ bias, void* __restrict__ Cout,
    u16* __restrict__ vtp, int M, int N)
{
    constexpr int BM = WMT * 32;
    constexpr int APASS = BM / 32;
    __shared__ u16 sAB[(BM + 128) * 64];
    u16* sA = sAB;
    u16* sB = sAB + BM * 64;

    const int tid  = threadIdx.x;
    const int lane = tid & 63;
    const int wave = tid >> 6;
    const int quad = lane >> 4;
    const int l16  = lane & 15;
    const int wm = wave >> 1, wn = wave & 1;
    const int m0 = blockIdx.y * BM;
    const int n0 = blockIdx.x * 128;

    const int srow = tid >> 3;      // staging row (+32/pass)
    const int schk = tid & 7;       // 16B chunk

    const u16* ag[APASS]; int aldw[APASS];
#pragma unroll
    for (int p = 0; p < APASS; ++p) {
        int row = p * 32 + srow;
        ag[p] = Ag + (size_t)(m0 + row) * EE + ((schk ^ (row & 7)) << 3);
        aldw[p] = (p * 256 + wave * 64) * 8;
    }
    const u16* bg[4]; int bldw[4];
#pragma unroll
    for (int p = 0; p < 4; ++p) {
        int row = p * 32 + srow;
        bg[p] = Wg + (size_t)(n0 + row) * EE + ((schk ^ (row & 7)) << 3);
        bldw[p] = (p * 256 + wave * 64) * 8;
    }

    f32x4 acc[WMT][4];
#pragma unroll
    for (int mt = 0; mt < WMT; ++mt)
#pragma unroll
        for (int nt = 0; nt < 4; ++nt) acc[mt][nt] = (f32x4){0.f, 0.f, 0.f, 0.f};

    for (int k0 = 0; k0 < EE; k0 += 64) {
        __syncthreads();
#pragma unroll
        for (int p = 0; p < APASS; ++p) async_ld16(ag[p] + k0, sA + aldw[p]);
#pragma unroll
        for (int p = 0; p < 4; ++p)    async_ld16(bg[p] + k0, sB + bldw[p]);
        __syncthreads();

        half8 fa[WMT][2], fb[4][2];
#pragma unroll
        for (int mt = 0; mt < WMT; ++mt) {
            int r = wm * (WMT * 16) + mt * 16 + l16;
#pragma unroll
            for (int ks = 0; ks < 2; ++ks)
                fa[mt][ks] = *(const half8*)&sA[r * 64 + (((ks * 4 + quad) ^ (r & 7)) << 3)];
        }
#pragma unroll
        for (int nt = 0; nt < 4; ++nt) {
            int r = wn * 64 + nt * 16 + l16;
#pragma unroll
            for (int ks = 0; ks < 2; ++ks)
                fb[nt][ks] = *(const half8*)&sB[r * 64 + (((ks * 4 + quad) ^ (r & 7)) << 3)];
        }
#pragma unroll
        for (int ks = 0; ks < 2; ++ks)
#pragma unroll
            for (int mt = 0; mt < WMT; ++mt)
#pragma unroll
                for (int nt = 0; nt < 4; ++nt)
                    acc[mt][nt] = __builtin_amdgcn_mfma_f32_16x16x32_f16(
                        fa[mt][ks], fb[nt][ks], acc[mt][nt], 0, 0, 0);
    }

    const float scale = (QSCALE && n0 < EE) ? 0.18033688011112042f : 1.0f;
    float bv[4];
#pragma unroll
    for (int nt = 0; nt < 4; ++nt) bv[nt] = bias[n0 + wn * 64 + nt * 16 + l16];

    if constexpr (F16OUT) {
        if (vtp != nullptr && n0 >= 2 * EE) {
            // ---- V block: transpose via LDS, store vt[b][h][d][t] ----
            __syncthreads();                 // all waves done with sA/sB
            u16* tile = sAB;                 // [128 c][32 units of 8B], swz
#pragma unroll
            for (int mt = 0; mt < WMT; ++mt)
#pragma unroll
                for (int nt = 0; nt < 4; ++nt) {
                    int c  = wn * 64 + nt * 16 + l16;
                    int ub = (wm * 16 + mt * 4 + quad) ^ ((c & 7) << 1);
                    *(uint2*)&tile[c * 128 + ub * 4] = make_uint2(
                        f2h(acc[mt][nt][0] + bv[nt]) | (f2h(acc[mt][nt][1] + bv[nt]) << 16),
                        f2h(acc[mt][nt][2] + bv[nt]) | (f2h(acc[mt][nt][3] + bv[nt]) << 16));
                }
            __syncthreads();
            // coalesced read-back: 8 lanes cover one d-row's 128 tokens
            const int t8 = tid & 7;
            const int bq = m0 >> 11;
            const int tokb = m0 & (TT - 1);
#pragma unroll
            for (int p = 0; p < 4; ++p) {
                int c  = p * 32 + (tid >> 3);      // tile column = d dim
                int hd = ((n0 - 2 * EE) >> 6) + (c >> 6);
                int d  = c & 63;
                u16* dst = vtp + ((size_t)(bq * HH + hd) * DD + d) * TT
                               + tokb + t8 * 16;
                int x = (c & 7) << 1;
#pragma unroll
                for (int j = 0; j < 2; ++j) {
                    int u = (t8 * 4 + j * 2) ^ x;  // even; phys pair contiguous
                    *(uint4*)(dst + j * 8) = *(const uint4*)&tile[c * 128 + u * 4];
                }
            }
            return;
        }
    }

#pragma unroll
    for (int mt = 0; mt < WMT; ++mt)
#pragma unroll
        for (int nt = 0; nt < 4; ++nt)
#pragma unroll
            for (int r = 0; r < 4; ++r) {
                int rg = m0 + wm * (WMT * 16) + mt * 16 + quad * 4 + r;
                int cg = n0 + wn * 64 + nt * 16 + l16;
                float v = (acc[mt][nt][r] + bv[nt]) * scale;
                if (F16OUT) ((u16*)Cout)[(size_t)rg * N + cg] = (u16)f2h(v);
                else        ((float*)Cout)[(size_t)rg * N + cg] = v;
            }
}

// R3-best flash attention (measured 53.2us): 32 q/wave, 4 waves (128 q),
// KVBLK=128, 64KB dbuf, in-register P (S^T C-layout == 16x16x16 B-layout),
// phase-split S->PV. R9: setprio REMOVED (R8 A/B: 53.2 -> 56.8 regression;
// our 4-wave lockstep block matches m190's null case, not m191's).
__global__ __launch_bounds__(256, 2) void attn_mfma(
    const u16* __restrict__ qkv, const u16* __restrict__ vt,
    u16* __restrict__ obuf)
{
    __shared__ u16 KB[2][128][64];   // [buf][key][d 16B-chunks ^ (key&7)]
    __shared__ u16 VB[2][64][128];   // [buf][d][key 16B-chunks ^ (d&15)]

    const int tid  = threadIdx.x;
    const int wave = tid >> 6;
    const int lane = tid & 63;
    const int quad = lane >> 4;
    const int l16  = lane & 15;

    const int q0 = blockIdx.x * 128;
    const int hh = blockIdx.y;
    const int b  = blockIdx.z;

    const int srow  = tid >> 3;      // K staging: 0..31 rows/pass
    const int schk  = tid & 7;
    const int vsrow = tid >> 4;      // V staging: 0..15 rows/pass
    const int vschk = tid & 15;
    const int ldsw  = wave * 512;    // u16: per-wave 1 KB chunk per pass

    // ---- Q fragments straight from global (once, 4 x 16B per lane) ----
    half8 qb[2][2];
#pragma unroll
    for (int qt = 0; qt < 2; ++qt) {
        int row = q0 + wave * 32 + qt * 16 + l16;
        const u16* qg = qkv + (size_t)(b * TT + row) * E3 + hh * DD;
#pragma unroll
        for (int ks = 0; ks < 2; ++ks)
            qb[qt][ks] = *(const half8*)(qg + ks * 32 + quad * 8);
    }

    // ---- stage K/V tile 0 (4 passes each) ----
#pragma unroll
    for (int p = 0; p < 4; ++p) {
        int krow = p * 32 + srow;
        async_ld16(qkv + (size_t)(b * TT + krow) * E3 + EE + hh * DD
                       + ((schk ^ (krow & 7)) << 3),
                   &KB[0][0][0] + p * 2048 + ldsw);
        int vrow = p * 16 + vsrow;
        async_ld16(vt + ((size_t)(b * HH + hh) * DD + vrow) * TT
                      + ((vschk ^ (vrow & 15)) << 3),
                   &VB[0][0][0] + p * 2048 + ldsw);
    }
    __syncthreads();

    const f32x4 Z = {0.f, 0.f, 0.f, 0.f};
    float l_i[2] = {0.f, 0.f};
    f32x4 o[4][2];                   // [dt][qt]
#pragma unroll
    for (int dt = 0; dt < 4; ++dt)
#pragma unroll
        for (int qt = 0; qt < 2; ++qt) o[dt][qt] = (f32x4){0.f, 0.f, 0.f, 0.f};

    int cur = 0;
    for (int kt = 0; kt < TT; kt += 128, cur ^= 1) {
        // ---- prefetch next K/V tile into alternate buffer ----
        const int ktn = (kt + 128) & (TT - 1);
#pragma unroll
        for (int p = 0; p < 4; ++p) {
            int krow = p * 32 + srow;
            async_ld16(qkv + (size_t)(b * TT + ktn + krow) * E3 + EE + hh * DD
                           + ((schk ^ (krow & 7)) << 3),
                       &KB[cur ^ 1][0][0] + p * 2048 + ldsw);
            int vrow = p * 16 + vsrow;
            async_ld16(vt + ((size_t)(b * HH + hh) * DD + vrow) * TT + ktn
                          + ((vschk ^ (vrow & 15)) << 3),
                       &VB[cur ^ 1][0][0] + p * 2048 + ldsw);
        }

        // ---- phase 1: S^T for all 8 key-groups, exp2+pack in-register ----
        half4 pb[2][8];
#pragma unroll
        for (int kg = 0; kg < 8; ++kg) {
            int r0 = kg * 16 + l16;
            half8 kf0 = *(const half8*)&KB[cur][r0][((quad)     ^ (r0 & 7)) << 3];
            half8 kf1 = *(const half8*)&KB[cur][r0][((4 + quad) ^ (r0 & 7)) << 3];
#pragma unroll
            for (int qt = 0; qt < 2; ++qt) {
                f32x4 t = __builtin_amdgcn_mfma_f32_16x16x32_f16(kf0, qb[qt][0], Z, 0, 0, 0);
                f32x4 s = __builtin_amdgcn_mfma_f32_16x16x32_f16(kf1, qb[qt][1], t, 0, 0, 0);
                float p0 = __builtin_amdgcn_exp2f(s[0]);
                float p1 = __builtin_amdgcn_exp2f(s[1]);
                float p2 = __builtin_amdgcn_exp2f(s[2]);
                float p3 = __builtin_amdgcn_exp2f(s[3]);
                l_i[qt] += (p0 + p1) + (p2 + p3);
                union { fp16x2 h[2]; half4 v; } u;
                u.h[0] = pk2(p0, p1);
                u.h[1] = pk2(p2, p3);
                pb[qt][kg] = u.v;    // B-frag of 16x16x16: k = quad*4+r, col = l16
            }
        }

        // ---- phase 2: O^T += V^T * P^T (32 b64 reads || 64 MFMAs) ----
#pragma unroll
        for (int kg = 0; kg < 8; ++kg) {
            int c = kg * 2 + (quad >> 1);
#pragma unroll
            for (int dt = 0; dt < 4; ++dt) {
                int vr = dt * 16 + l16;
                half4 vf = *(const half4*)&VB[cur][vr]
                               [((c ^ l16) << 3) + ((quad & 1) << 2)];
                o[dt][0] = __builtin_amdgcn_mfma_f32_16x16x16f16(vf, pb[0][kg], o[dt][0], 0, 0, 0);
                o[dt][1] = __builtin_amdgcn_mfma_f32_16x16x16f16(vf, pb[1][kg], o[dt][1], 0, 0, 0);
            }
        }

        __syncthreads();   // publishes prefetch + closes buffer swap
    }

    // ---- epilogue: reduce l over quad-groups, normalize, store f16 ----
    float inv[2];
#pragma unroll
    for (int qt = 0; qt < 2; ++qt) {
        float l = l_i[qt];
        l += __shfl_xor(l, 16, 64);
        l += __shfl_xor(l, 32, 64);
        inv[qt] = 1.f / l;
    }
#pragma unroll
    for (int qt = 0; qt < 2; ++qt) {
        size_t base = (size_t)(b * TT + q0 + wave * 32 + qt * 16 + l16) * EE + hh * DD;
#pragma unroll
        for (int dt = 0; dt < 4; ++dt) {
            unsigned hv[4];
#pragma unroll
            for (int r = 0; r < 4; ++r) hv[r] = f2h(o[dt][qt][r] * inv[qt]);
            *(uint2*)&obuf[base + dt * 16 + quad * 4] =
                make_uint2(hv[0] | (hv[1] << 16), hv[2] | (hv[3] << 16));
        }
    }
}

extern "C" void kernel_launch(void* const* d_in, const int* in_sizes, int n_in,
                              void* d_out, int out_size, void* d_ws, size_t ws_size,
                              hipStream_t stream)
{
    const float* x     = (const float*)d_in[0];
    const float* qkv_w = (const float*)d_in[1];
    const float* qkv_b = (const float*)d_in[2];
    const float* out_w = (const float*)d_in[3];
    const float* out_b = (const float*)d_in[4];
    float* out = (float*)d_out;

    const size_t NX  = (size_t)NTOK * EE;
    const size_t NW1 = (size_t)E3 * EE;
    const size_t NW2 = (size_t)EE * EE;
    const size_t NQ  = (size_t)NTOK * E3;

    u16* ws   = (u16*)d_ws;
    u16* x_h  = ws;                 // reused as attn O (f16) after gemm1 consumes x
    u16* w1h  = ws + NX;
    u16* w2h  = w1h + NW1;
    u16* qkvb = w2h + NW2;
    u16* vtb  = qkvb + NQ;

    split3<<<dim3((unsigned)((NX + NW1 + NW2) / 4 / 256)), 256, 0, stream>>>(
        x, qkv_w, out_w, x_h, w1h, w2h);

    gemm_f16<4, true, true, 4><<<dim3(E3 / 128, NTOK / 128), 256, 0, stream>>>(
        x_h, w1h, qkv_b, (void*)qkvb, vtb, NTOK, E3);

    attn_mfma<<<dim3(TT / 128, HH, BB), 256, 0, stream>>>(qkvb, vtb, x_h);

    gemm_f16<2, false, false, 3><<<dim3(EE / 128, NTOK / 64), 256, 0, stream>>>(
        x_h, w2h, out_b, (void*)out, nullptr, NTOK, EE);
}

// Round 10
// 175.814 us; speedup vs baseline: 1.0839x; 1.0839x over previous
//
#include <hip/hip_runtime.h>

#define TT 2048
#define BB 2
#define EE 1024
#define HH 16
#define DD 64
#define E3 3072
#define NTOK 4096

typedef unsigned short u16;
typedef _Float16 __attribute__((ext_vector_type(8))) half8;
typedef _Float16 __attribute__((ext_vector_type(4))) half4;
typedef __fp16 __attribute__((ext_vector_type(2))) fp16x2;
typedef __attribute__((ext_vector_type(4))) float f32x4;

__device__ __forceinline__ unsigned f2h(float f) {
    union { _Float16 h; u16 u; } v; v.h = (_Float16)f; return (unsigned)v.u;
}
// packed f32x2 -> f16x2 (round-toward-zero), one VALU op
__device__ __forceinline__ unsigned pkh(float a, float b) {
    union { fp16x2 h; unsigned u; } v;
    v.h = __builtin_amdgcn_cvt_pkrtz(a, b);
    return v.u;
}
__device__ __forceinline__ fp16x2 pk2(float a, float b) {
    return __builtin_amdgcn_cvt_pkrtz(a, b);
}

// async global->LDS, 16 B per lane; lds ptr must be wave-uniform
__device__ __forceinline__ void async_ld16(const u16* g, const u16* l) {
    auto gp = reinterpret_cast<const __attribute__((address_space(1))) unsigned*>(
        reinterpret_cast<uintptr_t>(g));
    auto lp = reinterpret_cast<__attribute__((address_space(3))) unsigned*>(
        reinterpret_cast<uintptr_t>(l));
    __builtin_amdgcn_global_load_lds(gp, lp, 16, 0, 0);
}

// fp32 -> f16 convert for x, qkv_w, out_w in ONE launch.
__global__ __launch_bounds__(256) void split3(
    const float* __restrict__ x, const float* __restrict__ w1,
    const float* __restrict__ w2,
    u16* __restrict__ xh, u16* __restrict__ w1h, u16* __restrict__ w2h)
{
    const int N1 = (NTOK * EE) / 4;
    const int N2 = N1 + (E3 * EE) / 4;
    int i = blockIdx.x * 256 + threadIdx.x;
    const float* src; u16* dst; int j;
    if (i < N1)      { src = x;  dst = xh;  j = i; }
    else if (i < N2) { src = w1; dst = w1h; j = i - N1; }
    else             { src = w2; dst = w2h; j = i - N2; }
    float4 v = ((const float4*)src)[j];
    *(uint2*)&dst[(size_t)j * 4] = make_uint2(
        f2h(v.x) | (f2h(v.y) << 16), f2h(v.z) | (f2h(v.w) << 16));
}

// f16 MFMA GEMM, BK=64. C[M,N] = A[M,1024] @ W[N,1024]^T + bias.
// QSCALE: q-third (n0<EE) scaled by 0.125*log2(e) so attention exp2s raw S.
// V-FUSION (F16OUT && vtp && n0>=2E): transpose the 128x128 tile through the
// dead sA/sB LDS, coalesced read-back (8 lanes = one d-row's 128 tokens).
// R10: OCC reverted to 3 (R9's OCC=4 forced 128-VGPR cap -> spills, +17us).
// XCD swizzle (T1): chunked bijective remap (nwg%8==0) so each XCD's L2
// keeps consecutive m-panels of A.
template <int WMT, bool QSCALE, bool F16OUT>
__global__ __launch_bounds__(256, 3) void gemm_f16(
    const u16* __restrict__ Ag, const u16* __restrict__ Wg,
    const float* __restrict__ bias, void* __restrict__ Cout,
    u16* __restrict__ vtp, int M, int N)
{
    constexpr int BM = WMT * 32;
    constexpr int APASS = BM / 32;
    __shared__ u16 sAB[(BM + 128) * 64];
    u16* sA = sAB;
    u16* sB = sAB + BM * 64;

    const int tid  = threadIdx.x;
    const int lane = tid & 63;
    const int wave = tid >> 6;
    const int quad = lane >> 4;
    const int l16  = lane & 15;
    const int wm = wave >> 1, wn = wave & 1;

    // XCD-aware chunked swizzle (grids are multiples of 8)
    const unsigned nwgx = gridDim.x;
    const unsigned flat = blockIdx.y * nwgx + blockIdx.x;
    const unsigned nwg  = nwgx * gridDim.y;
    const unsigned Wb   = (flat & 7) * (nwg >> 3) + (flat >> 3);
    const int m0 = (int)(Wb / nwgx) * BM;
    const int n0 = (int)(Wb % nwgx) * 128;

    const int srow = tid >> 3;      // staging row (+32/pass)
    const int schk = tid & 7;       // 16B chunk

    const u16* ag[APASS]; int aldw[APASS];
#pragma unroll
    for (int p = 0; p < APASS; ++p) {
        int row = p * 32 + srow;
        ag[p] = Ag + (size_t)(m0 + row) * EE + ((schk ^ (row & 7)) << 3);
        aldw[p] = (p * 256 + wave * 64) * 8;
    }
    const u16* bg[4]; int bldw[4];
#pragma unroll
    for (int p = 0; p < 4; ++p) {
        int row = p * 32 + srow;
        bg[p] = Wg + (size_t)(n0 + row) * EE + ((schk ^ (row & 7)) << 3);
        bldw[p] = (p * 256 + wave * 64) * 8;
    }

    f32x4 acc[WMT][4];
#pragma unroll
    for (int mt = 0; mt < WMT; ++mt)
#pragma unroll
        for (int nt = 0; nt < 4; ++nt) acc[mt][nt] = (f32x4){0.f, 0.f, 0.f, 0.f};

    for (int k0 = 0; k0 < EE; k0 += 64) {
        __syncthreads();
#pragma unroll
        for (int p = 0; p < APASS; ++p) async_ld16(ag[p] + k0, sA + aldw[p]);
#pragma unroll
        for (int p = 0; p < 4; ++p)    async_ld16(bg[p] + k0, sB + bldw[p]);
        __syncthreads();

        half8 fa[WMT][2], fb[4][2];
#pragma unroll
        for (int mt = 0; mt < WMT; ++mt) {
            int r = wm * (WMT * 16) + mt * 16 + l16;
#pragma unroll
            for (int ks = 0; ks < 2; ++ks)
                fa[mt][ks] = *(const half8*)&sA[r * 64 + (((ks * 4 + quad) ^ (r & 7)) << 3)];
        }
#pragma unroll
        for (int nt = 0; nt < 4; ++nt) {
            int r = wn * 64 + nt * 16 + l16;
#pragma unroll
            for (int ks = 0; ks < 2; ++ks)
                fb[nt][ks] = *(const half8*)&sB[r * 64 + (((ks * 4 + quad) ^ (r & 7)) << 3)];
        }
#pragma unroll
        for (int ks = 0; ks < 2; ++ks)
#pragma unroll
            for (int mt = 0; mt < WMT; ++mt)
#pragma unroll
                for (int nt = 0; nt < 4; ++nt)
                    acc[mt][nt] = __builtin_amdgcn_mfma_f32_16x16x32_f16(
                        fa[mt][ks], fb[nt][ks], acc[mt][nt], 0, 0, 0);
    }

    const float scale = (QSCALE && n0 < EE) ? 0.18033688011112042f : 1.0f;
    float bv[4];
#pragma unroll
    for (int nt = 0; nt < 4; ++nt) bv[nt] = bias[n0 + wn * 64 + nt * 16 + l16];

    if constexpr (F16OUT) {
        if (vtp != nullptr && n0 >= 2 * EE) {
            // ---- V block: transpose via LDS, store vt[b][h][d][t] ----
            __syncthreads();                 // all waves done with sA/sB
            u16* tile = sAB;                 // [128 c][32 units of 8B], swz
#pragma unroll
            for (int mt = 0; mt < WMT; ++mt)
#pragma unroll
                for (int nt = 0; nt < 4; ++nt) {
                    int c  = wn * 64 + nt * 16 + l16;
                    int ub = (wm * 16 + mt * 4 + quad) ^ ((c & 7) << 1);
                    *(uint2*)&tile[c * 128 + ub * 4] = make_uint2(
                        f2h(acc[mt][nt][0] + bv[nt]) | (f2h(acc[mt][nt][1] + bv[nt]) << 16),
                        f2h(acc[mt][nt][2] + bv[nt]) | (f2h(acc[mt][nt][3] + bv[nt]) << 16));
                }
            __syncthreads();
            // coalesced read-back: 8 lanes cover one d-row's 128 tokens
            const int t8 = tid & 7;
            const int bq = m0 >> 11;
            const int tokb = m0 & (TT - 1);
#pragma unroll
            for (int p = 0; p < 4; ++p) {
                int c  = p * 32 + (tid >> 3);      // tile column = d dim
                int hd = ((n0 - 2 * EE) >> 6) + (c >> 6);
                int d  = c & 63;
                u16* dst = vtp + ((size_t)(bq * HH + hd) * DD + d) * TT
                               + tokb + t8 * 16;
                int x = (c & 7) << 1;
#pragma unroll
                for (int j = 0; j < 2; ++j) {
                    int u = (t8 * 4 + j * 2) ^ x;  // even; phys pair contiguous
                    *(uint4*)(dst + j * 8) = *(const uint4*)&tile[c * 128 + u * 4];
                }
            }
            return;
        }
    }

#pragma unroll
    for (int mt = 0; mt < WMT; ++mt)
#pragma unroll
        for (int nt = 0; nt < 4; ++nt)
#pragma unroll
            for (int r = 0; r < 4; ++r) {
                int rg = m0 + wm * (WMT * 16) + mt * 16 + quad * 4 + r;
                int cg = n0 + wn * 64 + nt * 16 + l16;
                float v = (acc[mt][nt][r] + bv[nt]) * scale;
                if (F16OUT) ((u16*)Cout)[(size_t)rg * N + cg] = (u16)f2h(v);
                else        ((float*)Cout)[(size_t)rg * N + cg] = v;
            }
}

// R3-best flash attention (measured 52.7-53.3us): 32 q/wave, 4 waves (128 q),
// KVBLK=128, 64KB dbuf, in-register P (S^T C-layout == 16x16x16 B-layout),
// phase-split S->PV, no setprio. R10: XCD swizzle — 512 blocks chunked so
// each XCD's L2 serves 4 (head,batch) pairs (2MB K/V working set < 4MB L2)
// instead of round-robining every head across all 8 XCDs (FETCH 73.8MB).
__global__ __launch_bounds__(256, 2) void attn_mfma(
    const u16* __restrict__ qkv, const u16* __restrict__ vt,
    u16* __restrict__ obuf)
{
    __shared__ u16 KB[2][128][64];   // [buf][key][d 16B-chunks ^ (key&7)]
    __shared__ u16 VB[2][64][128];   // [buf][d][key 16B-chunks ^ (d&15)]

    const int tid  = threadIdx.x;
    const int wave = tid >> 6;
    const int lane = tid & 63;
    const int quad = lane >> 4;
    const int l16  = lane & 15;

    // XCD-aware chunked swizzle: flat 0..511, W = (flat%8)*64 + flat/8
    const unsigned flat = blockIdx.x + 16 * blockIdx.y + 256 * blockIdx.z;
    const unsigned Wb   = (flat & 7) * 64 + (flat >> 3);
    const int q0 = (int)(Wb & 15) * 128;
    const int hh = (int)(Wb >> 4) & 15;
    const int b  = (int)(Wb >> 8);

    const int srow  = tid >> 3;      // K staging: 0..31 rows/pass
    const int schk  = tid & 7;
    const int vsrow = tid >> 4;      // V staging: 0..15 rows/pass
    const int vschk = tid & 15;
    const int ldsw  = wave * 512;    // u16: per-wave 1 KB chunk per pass

    // ---- Q fragments straight from global (once, 4 x 16B per lane) ----
    half8 qb[2][2];
#pragma unroll
    for (int qt = 0; qt < 2; ++qt) {
        int row = q0 + wave * 32 + qt * 16 + l16;
        const u16* qg = qkv + (size_t)(b * TT + row) * E3 + hh * DD;
#pragma unroll
        for (int ks = 0; ks < 2; ++ks)
            qb[qt][ks] = *(const half8*)(qg + ks * 32 + quad * 8);
    }

    // ---- stage K/V tile 0 (4 passes each) ----
#pragma unroll
    for (int p = 0; p < 4; ++p) {
        int krow = p * 32 + srow;
        async_ld16(qkv + (size_t)(b * TT + krow) * E3 + EE + hh * DD
                       + ((schk ^ (krow & 7)) << 3),
                   &KB[0][0][0] + p * 2048 + ldsw);
        int vrow = p * 16 + vsrow;
        async_ld16(vt + ((size_t)(b * HH + hh) * DD + vrow) * TT
                      + ((vschk ^ (vrow & 15)) << 3),
                   &VB[0][0][0] + p * 2048 + ldsw);
    }
    __syncthreads();

    const f32x4 Z = {0.f, 0.f, 0.f, 0.f};
    float l_i[2] = {0.f, 0.f};
    f32x4 o[4][2];                   // [dt][qt]
#pragma unroll
    for (int dt = 0; dt < 4; ++dt)
#pragma unroll
        for (int qt = 0; qt < 2; ++qt) o[dt][qt] = (f32x4){0.f, 0.f, 0.f, 0.f};

    int cur = 0;
    for (int kt = 0; kt < TT; kt += 128, cur ^= 1) {
        // ---- prefetch next K/V tile into alternate buffer ----
        const int ktn = (kt + 128) & (TT - 1);
#pragma unroll
        for (int p = 0; p < 4; ++p) {
            int krow = p * 32 + srow;
            async_ld16(qkv + (size_t)(b * TT + ktn + krow) * E3 + EE + hh * DD
                           + ((schk ^ (krow & 7)) << 3),
                       &KB[cur ^ 1][0][0] + p * 2048 + ldsw);
            int vrow = p * 16 + vsrow;
            async_ld16(vt + ((size_t)(b * HH + hh) * DD + vrow) * TT + ktn
                          + ((vschk ^ (vrow & 15)) << 3),
                       &VB[cur ^ 1][0][0] + p * 2048 + ldsw);
        }

        // ---- phase 1: S^T for all 8 key-groups, exp2+pack in-register ----
        half4 pb[2][8];
#pragma unroll
        for (int kg = 0; kg < 8; ++kg) {
            int r0 = kg * 16 + l16;
            half8 kf0 = *(const half8*)&KB[cur][r0][((quad)     ^ (r0 & 7)) << 3];
            half8 kf1 = *(const half8*)&KB[cur][r0][((4 + quad) ^ (r0 & 7)) << 3];
#pragma unroll
            for (int qt = 0; qt < 2; ++qt) {
                f32x4 t = __builtin_amdgcn_mfma_f32_16x16x32_f16(kf0, qb[qt][0], Z, 0, 0, 0);
                f32x4 s = __builtin_amdgcn_mfma_f32_16x16x32_f16(kf1, qb[qt][1], t, 0, 0, 0);
                float p0 = __builtin_amdgcn_exp2f(s[0]);
                float p1 = __builtin_amdgcn_exp2f(s[1]);
                float p2 = __builtin_amdgcn_exp2f(s[2]);
                float p3 = __builtin_amdgcn_exp2f(s[3]);
                l_i[qt] += (p0 + p1) + (p2 + p3);
                union { fp16x2 h[2]; half4 v; } u;
                u.h[0] = pk2(p0, p1);
                u.h[1] = pk2(p2, p3);
                pb[qt][kg] = u.v;    // B-frag of 16x16x16: k = quad*4+r, col = l16
            }
        }

        // ---- phase 2: O^T += V^T * P^T (32 b64 reads || 64 MFMAs) ----
#pragma unroll
        for (int kg = 0; kg < 8; ++kg) {
            int c = kg * 2 + (quad >> 1);
#pragma unroll
            for (int dt = 0; dt < 4; ++dt) {
                int vr = dt * 16 + l16;
                half4 vf = *(const half4*)&VB[cur][vr]
                               [((c ^ l16) << 3) + ((quad & 1) << 2)];
                o[dt][0] = __builtin_amdgcn_mfma_f32_16x16x16f16(vf, pb[0][kg], o[dt][0], 0, 0, 0);
                o[dt][1] = __builtin_amdgcn_mfma_f32_16x16x16f16(vf, pb[1][kg], o[dt][1], 0, 0, 0);
            }
        }

        __syncthreads();   // publishes prefetch + closes buffer swap
    }

    // ---- epilogue: reduce l over quad-groups, normalize, store f16 ----
    float inv[2];
#pragma unroll
    for (int qt = 0; qt < 2; ++qt) {
        float l = l_i[qt];
        l += __shfl_xor(l, 16, 64);
        l += __shfl_xor(l, 32, 64);
        inv[qt] = 1.f / l;
    }
#pragma unroll
    for (int qt = 0; qt < 2; ++qt) {
        size_t base = (size_t)(b * TT + q0 + wave * 32 + qt * 16 + l16) * EE + hh * DD;
#pragma unroll
        for (int dt = 0; dt < 4; ++dt) {
            unsigned hv[4];
#pragma unroll
            for (int r = 0; r < 4; ++r) hv[r] = f2h(o[dt][qt][r] * inv[qt]);
            *(uint2*)&obuf[base + dt * 16 + quad * 4] =
                make_uint2(hv[0] | (hv[1] << 16), hv[2] | (hv[3] << 16));
        }
    }
}

extern "C" void kernel_launch(void* const* d_in, const int* in_sizes, int n_in,
                              void* d_out, int out_size, void* d_ws, size_t ws_size,
                              hipStream_t stream)
{
    const float* x     = (const float*)d_in[0];
    const float* qkv_w = (const float*)d_in[1];
    const float* qkv_b = (const float*)d_in[2];
    const float* out_w = (const float*)d_in[3];
    const float* out_b = (const float*)d_in[4];
    float* out = (float*)d_out;

    const size_t NX  = (size_t)NTOK * EE;
    const size_t NW1 = (size_t)E3 * EE;
    const size_t NW2 = (size_t)EE * EE;
    const size_t NQ  = (size_t)NTOK * E3;

    u16* ws   = (u16*)d_ws;
    u16* x_h  = ws;                 // reused as attn O (f16) after gemm1 consumes x
    u16* w1h  = ws + NX;
    u16* w2h  = w1h + NW1;
    u16* qkvb = w2h + NW2;
    u16* vtb  = qkvb + NQ;

    split3<<<dim3((unsigned)((NX + NW1 + NW2) / 4 / 256)), 256, 0, stream>>>(
        x, qkv_w, out_w, x_h, w1h, w2h);

    gemm_f16<4, true, true><<<dim3(E3 / 128, NTOK / 128), 256, 0, stream>>>(
        x_h, w1h, qkv_b, (void*)qkvb, vtb, NTOK, E3);

    attn_mfma<<<dim3(TT / 128, HH, BB), 256, 0, stream>>>(qkvb, vtb, x_h);

    gemm_f16<2, false, false><<<dim3(EE / 128, NTOK / 64), 256, 0, stream>>>(
        x_h, w2h, out_b, (void*)out, nullptr, NTOK, EE);
}

// Round 11
// 173.494 us; speedup vs baseline: 1.0984x; 1.0134x over previous
//
#include <hip/hip_runtime.h>

#define TT 2048
#define BB 2
#define EE 1024
#define HH 16
#define DD 64
#define E3 3072
#define NTOK 4096

typedef unsigned short u16;
typedef _Float16 __attribute__((ext_vector_type(8))) half8;
typedef _Float16 __attribute__((ext_vector_type(4))) half4;
typedef __fp16 __attribute__((ext_vector_type(2))) fp16x2;
typedef __attribute__((ext_vector_type(4))) float f32x4;

union PW { half4 h[2]; half8 v; };

__device__ __forceinline__ unsigned f2h(float f) {
    union { _Float16 h; u16 u; } v; v.h = (_Float16)f; return (unsigned)v.u;
}
// packed f32x2 -> f16x2 (round-toward-zero), one VALU op
__device__ __forceinline__ unsigned pkh(float a, float b) {
    union { fp16x2 h; unsigned u; } v;
    v.h = __builtin_amdgcn_cvt_pkrtz(a, b);
    return v.u;
}
__device__ __forceinline__ fp16x2 pk2(float a, float b) {
    return __builtin_amdgcn_cvt_pkrtz(a, b);
}

// async global->LDS, 16 B per lane; lds ptr must be wave-uniform
__device__ __forceinline__ void async_ld16(const u16* g, const u16* l) {
    auto gp = reinterpret_cast<const __attribute__((address_space(1))) unsigned*>(
        reinterpret_cast<uintptr_t>(g));
    auto lp = reinterpret_cast<__attribute__((address_space(3))) unsigned*>(
        reinterpret_cast<uintptr_t>(l));
    __builtin_amdgcn_global_load_lds(gp, lp, 16, 0, 0);
}

// fp32 -> f16 convert for x, qkv_w, out_w in ONE launch.
__global__ __launch_bounds__(256) void split3(
    const float* __restrict__ x, const float* __restrict__ w1,
    const float* __restrict__ w2,
    u16* __restrict__ xh, u16* __restrict__ w1h, u16* __restrict__ w2h)
{
    const int N1 = (NTOK * EE) / 4;
    const int N2 = N1 + (E3 * EE) / 4;
    int i = blockIdx.x * 256 + threadIdx.x;
    const float* src; u16* dst; int j;
    if (i < N1)      { src = x;  dst = xh;  j = i; }
    else if (i < N2) { src = w1; dst = w1h; j = i - N1; }
    else             { src = w2; dst = w2h; j = i - N2; }
    float4 v = ((const float4*)src)[j];
    *(uint2*)&dst[(size_t)j * 4] = make_uint2(
        f2h(v.x) | (f2h(v.y) << 16), f2h(v.z) | (f2h(v.w) << 16));
}

// f16 MFMA GEMM, BK=64. C[M,N] = A[M,1024] @ W[N,1024]^T + bias.
// QSCALE: q-third (n0<EE) scaled by 0.125*log2(e) so attention exp2s raw S.
// V-FUSION (F16OUT && vtp && n0>=2E): transpose the 128x128 tile through the
// dead sA/sB LDS, coalesced read-back (8 lanes = one d-row's 128 tokens).
// XCD swizzle: chunked bijective remap (nwg%8==0), neutral on time, -6x HBM.
template <int WMT, bool QSCALE, bool F16OUT>
__global__ __launch_bounds__(256, 3) void gemm_f16(
    const u16* __restrict__ Ag, const u16* __restrict__ Wg,
    const float* __restrict__ bias, void* __restrict__ Cout,
    u16* __restrict__ vtp, int M, int N)
{
    constexpr int BM = WMT * 32;
    constexpr int APASS = BM / 32;
    __shared__ u16 sAB[(BM + 128) * 64];
    u16* sA = sAB;
    u16* sB = sAB + BM * 64;

    const int tid  = threadIdx.x;
    const int lane = tid & 63;
    const int wave = tid >> 6;
    const int quad = lane >> 4;
    const int l16  = lane & 15;
    const int wm = wave >> 1, wn = wave & 1;

    // XCD-aware chunked swizzle (grids are multiples of 8)
    const unsigned nwgx = gridDim.x;
    const unsigned flat = blockIdx.y * nwgx + blockIdx.x;
    const unsigned nwg  = nwgx * gridDim.y;
    const unsigned Wb   = (flat & 7) * (nwg >> 3) + (flat >> 3);
    const int m0 = (int)(Wb / nwgx) * BM;
    const int n0 = (int)(Wb % nwgx) * 128;

    const int srow = tid >> 3;      // staging row (+32/pass)
    const int schk = tid & 7;       // 16B chunk

    const u16* ag[APASS]; int aldw[APASS];
#pragma unroll
    for (int p = 0; p < APASS; ++p) {
        int row = p * 32 + srow;
        ag[p] = Ag + (size_t)(m0 + row) * EE + ((schk ^ (row & 7)) << 3);
        aldw[p] = (p * 256 + wave * 64) * 8;
    }
    const u16* bg[4]; int bldw[4];
#pragma unroll
    for (int p = 0; p < 4; ++p) {
        int row = p * 32 + srow;
        bg[p] = Wg + (size_t)(n0 + row) * EE + ((schk ^ (row & 7)) << 3);
        bldw[p] = (p * 256 + wave * 64) * 8;
    }

    f32x4 acc[WMT][4];
#pragma unroll
    for (int mt = 0; mt < WMT; ++mt)
#pragma unroll
        for (int nt = 0; nt < 4; ++nt) acc[mt][nt] = (f32x4){0.f, 0.f, 0.f, 0.f};

    for (int k0 = 0; k0 < EE; k0 += 64) {
        __syncthreads();
#pragma unroll
        for (int p = 0; p < APASS; ++p) async_ld16(ag[p] + k0, sA + aldw[p]);
#pragma unroll
        for (int p = 0; p < 4; ++p)    async_ld16(bg[p] + k0, sB + bldw[p]);
        __syncthreads();

        half8 fa[WMT][2], fb[4][2];
#pragma unroll
        for (int mt = 0; mt < WMT; ++mt) {
            int r = wm * (WMT * 16) + mt * 16 + l16;
#pragma unroll
            for (int ks = 0; ks < 2; ++ks)
                fa[mt][ks] = *(const half8*)&sA[r * 64 + (((ks * 4 + quad) ^ (r & 7)) << 3)];
        }
#pragma unroll
        for (int nt = 0; nt < 4; ++nt) {
            int r = wn * 64 + nt * 16 + l16;
#pragma unroll
            for (int ks = 0; ks < 2; ++ks)
                fb[nt][ks] = *(const half8*)&sB[r * 64 + (((ks * 4 + quad) ^ (r & 7)) << 3)];
        }
#pragma unroll
        for (int ks = 0; ks < 2; ++ks)
#pragma unroll
            for (int mt = 0; mt < WMT; ++mt)
#pragma unroll
                for (int nt = 0; nt < 4; ++nt)
                    acc[mt][nt] = __builtin_amdgcn_mfma_f32_16x16x32_f16(
                        fa[mt][ks], fb[nt][ks], acc[mt][nt], 0, 0, 0);
    }

    const float scale = (QSCALE && n0 < EE) ? 0.18033688011112042f : 1.0f;
    float bv[4];
#pragma unroll
    for (int nt = 0; nt < 4; ++nt) bv[nt] = bias[n0 + wn * 64 + nt * 16 + l16];

    if constexpr (F16OUT) {
        if (vtp != nullptr && n0 >= 2 * EE) {
            // ---- V block: transpose via LDS, store vt[b][h][d][t] ----
            __syncthreads();                 // all waves done with sA/sB
            u16* tile = sAB;                 // [128 c][32 units of 8B], swz
#pragma unroll
            for (int mt = 0; mt < WMT; ++mt)
#pragma unroll
                for (int nt = 0; nt < 4; ++nt) {
                    int c  = wn * 64 + nt * 16 + l16;
                    int ub = (wm * 16 + mt * 4 + quad) ^ ((c & 7) << 1);
                    *(uint2*)&tile[c * 128 + ub * 4] = make_uint2(
                        f2h(acc[mt][nt][0] + bv[nt]) | (f2h(acc[mt][nt][1] + bv[nt]) << 16),
                        f2h(acc[mt][nt][2] + bv[nt]) | (f2h(acc[mt][nt][3] + bv[nt]) << 16));
                }
            __syncthreads();
            // coalesced read-back: 8 lanes cover one d-row's 128 tokens
            const int t8 = tid & 7;
            const int bq = m0 >> 11;
            const int tokb = m0 & (TT - 1);
#pragma unroll
            for (int p = 0; p < 4; ++p) {
                int c  = p * 32 + (tid >> 3);      // tile column = d dim
                int hd = ((n0 - 2 * EE) >> 6) + (c >> 6);
                int d  = c & 63;
                u16* dst = vtp + ((size_t)(bq * HH + hd) * DD + d) * TT
                               + tokb + t8 * 16;
                int x = (c & 7) << 1;
#pragma unroll
                for (int j = 0; j < 2; ++j) {
                    int u = (t8 * 4 + j * 2) ^ x;  // even; phys pair contiguous
                    *(uint4*)(dst + j * 8) = *(const uint4*)&tile[c * 128 + u * 4];
                }
            }
            return;
        }
    }

#pragma unroll
    for (int mt = 0; mt < WMT; ++mt)
#pragma unroll
        for (int nt = 0; nt < 4; ++nt)
#pragma unroll
            for (int r = 0; r < 4; ++r) {
                int rg = m0 + wm * (WMT * 16) + mt * 16 + quad * 4 + r;
                int cg = n0 + wn * 64 + nt * 16 + l16;
                float v = (acc[mt][nt][r] + bv[nt]) * scale;
                if (F16OUT) ((u16*)Cout)[(size_t)rg * N + cg] = (u16)f2h(v);
                else        ((float*)Cout)[(size_t)rg * N + cg] = v;
            }
}

// Flash attention: 32 q/wave, 4 waves (128 q/block), KVBLK=128, 64KB dbuf,
// in-register P, phase-split S->PV, no setprio, NO XCD swizzle (R10 A/B:
// swizzle -6x FETCH but +2.3us — attn is latency-bound, not BW-bound).
// R11: PV upgraded from legacy-rate 16x16x16 (half FLOPs per ~4.8cy issue
// slot) to full-rate 16x16x32. MFMA only needs A/B to agree on k-order, so
// the K=32 B-frag is defined as [4 keys of group 2w | 4 keys of group 2w+1]
// = concatenation of the two half4s the S-phase already packs (zero moves);
// the V A-frag reads those same 8 keys as two b64 (same 32 b64/iter as
// before). PV MFMA instrs/iter: 64 -> 32.
__global__ __launch_bounds__(256, 2) void attn_mfma(
    const u16* __restrict__ qkv, const u16* __restrict__ vt,
    u16* __restrict__ obuf)
{
    __shared__ u16 KB[2][128][64];   // [buf][key][d 16B-chunks ^ (key&7)]
    __shared__ u16 VB[2][64][128];   // [buf][d][key 16B-chunks ^ (d&15)]

    const int tid  = threadIdx.x;
    const int wave = tid >> 6;
    const int lane = tid & 63;
    const int quad = lane >> 4;
    const int l16  = lane & 15;

    const int q0 = blockIdx.x * 128;
    const int hh = blockIdx.y;
    const int b  = blockIdx.z;

    const int srow  = tid >> 3;      // K staging: 0..31 rows/pass
    const int schk  = tid & 7;
    const int vsrow = tid >> 4;      // V staging: 0..15 rows/pass
    const int vschk = tid & 15;
    const int ldsw  = wave * 512;    // u16: per-wave 1 KB chunk per pass

    // ---- Q fragments straight from global (once, 4 x 16B per lane) ----
    half8 qb[2][2];
#pragma unroll
    for (int qt = 0; qt < 2; ++qt) {
        int row = q0 + wave * 32 + qt * 16 + l16;
        const u16* qg = qkv + (size_t)(b * TT + row) * E3 + hh * DD;
#pragma unroll
        for (int ks = 0; ks < 2; ++ks)
            qb[qt][ks] = *(const half8*)(qg + ks * 32 + quad * 8);
    }

    // ---- stage K/V tile 0 (4 passes each) ----
#pragma unroll
    for (int p = 0; p < 4; ++p) {
        int krow = p * 32 + srow;
        async_ld16(qkv + (size_t)(b * TT + krow) * E3 + EE + hh * DD
                       + ((schk ^ (krow & 7)) << 3),
                   &KB[0][0][0] + p * 2048 + ldsw);
        int vrow = p * 16 + vsrow;
        async_ld16(vt + ((size_t)(b * HH + hh) * DD + vrow) * TT
                      + ((vschk ^ (vrow & 15)) << 3),
                   &VB[0][0][0] + p * 2048 + ldsw);
    }
    __syncthreads();

    const f32x4 Z = {0.f, 0.f, 0.f, 0.f};
    float l_i[2] = {0.f, 0.f};
    f32x4 o[4][2];                   // [dt][qt]
#pragma unroll
    for (int dt = 0; dt < 4; ++dt)
#pragma unroll
        for (int qt = 0; qt < 2; ++qt) o[dt][qt] = (f32x4){0.f, 0.f, 0.f, 0.f};

    int cur = 0;
    for (int kt = 0; kt < TT; kt += 128, cur ^= 1) {
        // ---- prefetch next K/V tile into alternate buffer ----
        const int ktn = (kt + 128) & (TT - 1);
#pragma unroll
        for (int p = 0; p < 4; ++p) {
            int krow = p * 32 + srow;
            async_ld16(qkv + (size_t)(b * TT + ktn + krow) * E3 + EE + hh * DD
                           + ((schk ^ (krow & 7)) << 3),
                       &KB[cur ^ 1][0][0] + p * 2048 + ldsw);
            int vrow = p * 16 + vsrow;
            async_ld16(vt + ((size_t)(b * HH + hh) * DD + vrow) * TT + ktn
                          + ((vschk ^ (vrow & 15)) << 3),
                       &VB[cur ^ 1][0][0] + p * 2048 + ldsw);
        }

        // ---- phase 1: S^T for all 8 key-groups, exp2+pack in-register.
        //      Packed half4s land directly in the lo/hi halves of the
        //      K=32 PV B-frags pw[qt][kg>>1] (static indices). ----
        PW pw[2][4];
#pragma unroll
        for (int kg = 0; kg < 8; ++kg) {
            int r0 = kg * 16 + l16;
            half8 kf0 = *(const half8*)&KB[cur][r0][((quad)     ^ (r0 & 7)) << 3];
            half8 kf1 = *(const half8*)&KB[cur][r0][((4 + quad) ^ (r0 & 7)) << 3];
#pragma unroll
            for (int qt = 0; qt < 2; ++qt) {
                f32x4 t = __builtin_amdgcn_mfma_f32_16x16x32_f16(kf0, qb[qt][0], Z, 0, 0, 0);
                f32x4 s = __builtin_amdgcn_mfma_f32_16x16x32_f16(kf1, qb[qt][1], t, 0, 0, 0);
                float p0 = __builtin_amdgcn_exp2f(s[0]);
                float p1 = __builtin_amdgcn_exp2f(s[1]);
                float p2 = __builtin_amdgcn_exp2f(s[2]);
                float p3 = __builtin_amdgcn_exp2f(s[3]);
                l_i[qt] += (p0 + p1) + (p2 + p3);
                union { fp16x2 h[2]; half4 v; } u;
                u.h[0] = pk2(p0, p1);
                u.h[1] = pk2(p2, p3);
                pw[qt][kg >> 1].h[kg & 1] = u.v;  // keys kg*16 + quad*4 + r
            }
        }

        // ---- phase 2: O^T += V^T * P^T, full-rate K=32 MFMAs.
        //      k-order: j<4 -> key 32w+4q+j, j>=4 -> key 32w+16+4q+(j-4);
        //      A (V) supplies the same keys via two b64 reads. ----
#pragma unroll
        for (int w = 0; w < 4; ++w) {
            const int cl  = w * 4 + (quad >> 1);
            const int sub = (quad & 1) << 2;
#pragma unroll
            for (int dt = 0; dt < 4; ++dt) {
                int vr = dt * 16 + l16;
                PW va;
                va.h[0] = *(const half4*)&VB[cur][vr][((cl       ^ l16) << 3) + sub];
                va.h[1] = *(const half4*)&VB[cur][vr][(((cl + 2) ^ l16) << 3) + sub];
                o[dt][0] = __builtin_amdgcn_mfma_f32_16x16x32_f16(va.v, pw[0][w].v, o[dt][0], 0, 0, 0);
                o[dt][1] = __builtin_amdgcn_mfma_f32_16x16x32_f16(va.v, pw[1][w].v, o[dt][1], 0, 0, 0);
            }
        }

        __syncthreads();   // publishes prefetch + closes buffer swap
    }

    // ---- epilogue: reduce l over quad-groups, normalize, store f16 ----
    float inv[2];
#pragma unroll
    for (int qt = 0; qt < 2; ++qt) {
        float l = l_i[qt];
        l += __shfl_xor(l, 16, 64);
        l += __shfl_xor(l, 32, 64);
        inv[qt] = 1.f / l;
    }
#pragma unroll
    for (int qt = 0; qt < 2; ++qt) {
        size_t base = (size_t)(b * TT + q0 + wave * 32 + qt * 16 + l16) * EE + hh * DD;
#pragma unroll
        for (int dt = 0; dt < 4; ++dt) {
            unsigned hv[4];
#pragma unroll
            for (int r = 0; r < 4; ++r) hv[r] = f2h(o[dt][qt][r] * inv[qt]);
            *(uint2*)&obuf[base + dt * 16 + quad * 4] =
                make_uint2(hv[0] | (hv[1] << 16), hv[2] | (hv[3] << 16));
        }
    }
}

extern "C" void kernel_launch(void* const* d_in, const int* in_sizes, int n_in,
                              void* d_out, int out_size, void* d_ws, size_t ws_size,
                              hipStream_t stream)
{
    const float* x     = (const float*)d_in[0];
    const float* qkv_w = (const float*)d_in[1];
    const float* qkv_b = (const float*)d_in[2];
    const float* out_w = (const float*)d_in[3];
    const float* out_b = (const float*)d_in[4];
    float* out = (float*)d_out;

    const size_t NX  = (size_t)NTOK * EE;
    const size_t NW1 = (size_t)E3 * EE;
    const size_t NW2 = (size_t)EE * EE;
    const size_t NQ  = (size_t)NTOK * E3;

    u16* ws   = (u16*)d_ws;
    u16* x_h  = ws;                 // reused as attn O (f16) after gemm1 consumes x
    u16* w1h  = ws + NX;
    u16* w2h  = w1h + NW1;
    u16* qkvb = w2h + NW2;
    u16* vtb  = qkvb + NQ;

    split3<<<dim3((unsigned)((NX + NW1 + NW2) / 4 / 256)), 256, 0, stream>>>(
        x, qkv_w, out_w, x_h, w1h, w2h);

    gemm_f16<4, true, true><<<dim3(E3 / 128, NTOK / 128), 256, 0, stream>>>(
        x_h, w1h, qkv_b, (void*)qkvb, vtb, NTOK, E3);

    attn_mfma<<<dim3(TT / 128, HH, BB), 256, 0, stream>>>(qkvb, vtb, x_h);

    gemm_f16<2, false, false><<<dim3(EE / 128, NTOK / 64), 256, 0, stream>>>(
        x_h, w2h, out_b, (void*)out, nullptr, NTOK, EE);
}